// Round 6
// baseline (108.188 us; speedup 1.0000x reference)
//
#include <hip/hip_runtime.h>

// Local 5x5 window dot-product attention (fp32). B=2, H=W=256, C=BIN=32.
//   attn[p,k] = dot_c(main[p,:], ref[p+off_k,:])   (0 if OOB; zero-padded)
//   w = softmax_k(attn)   (no-max softmax is exact: |s| <~ 30 for N(0,1) data)
//   out[p,:]  = sum_k w[k] * ref_value[p+off_k,:]
//
// R6: LDS staging. R1/R3/R5 all landed ~50us regardless of VMEM count ->
// latency-bound: every shifted window load went to L2/L3 (~200-600cy, L1
// thrashes on 25x shift reuse) and fed a short dependent chain. Fix: each
// block stages its 6-row x 36-col halo tile of ref AND ref_value into LDS
// once (coalesced, fully independent float4 loads -> deep MLP), then the
// 25x reuse is served from LDS (~120cy, contiguous conflict-free
// ds_read_b128). Compute structure = R5 (vertical x2, fully static, no-max
// streaming softmax, 3x shfl_xor score reduce). No local arrays (R4 lesson).
//
// LDS: 2 arrays x 6 x 36 x 128B = 55.3 KB -> 2 blocks/CU.
// Tile: 32 wide x 2 tall; block = 256 thr = 4 waves x (8 px-cols x 8 lanes).

#define LROWS 6                    // TILE_H(2) + 4 halo
#define LCOLS 36                   // TILE_W(32) + 4 halo
#define L4PERROW (LCOLS * 8)       // 288 float4 per staged row
#define L4TOTAL  (LROWS * L4PERROW)  // 1728 float4 per array

__global__ void __launch_bounds__(256)
local_attn_kernel(const float* __restrict__ main_p,
                  const float* __restrict__ ref_p,
                  const float* __restrict__ rv_p,
                  float* __restrict__ out_p)
{
    __shared__ float4 s_r[L4TOTAL];
    __shared__ float4 s_v[L4TOTAL];

    const int tid  = threadIdx.x;
    const int lane = tid & 63;
    const int wv   = tid >> 6;
    const int cg   = lane & 7;          // float4 index within pixel (4 channels)
    const int pw   = lane >> 3;         // pixel-column within wave: 0..7

    // grid: 2048 blocks; tile = 32 cols x 2 rows; 1024 tiles per image
    const int b     = blockIdx.x;
    const int batch = b >> 10;
    const int tb    = b & 1023;
    const int ty    = tb >> 3;          // 0..127 -> h0 = ty*2
    const int tx    = tb & 7;           // 0..7   -> tile col base = tx*32
    const int h0    = ty * 2;
    const int wt    = tx * 32;
    const int bbase = batch << 16;      // batch * H*W

    // source column window start, clamped so all 36 cols are in-bounds
    const int src_c0 = min(max(wt - 2, 0), 256 - LCOLS);

    const float4* m4 = (const float4*)main_p;
    const float4* r4 = (const float4*)ref_p;
    const float4* v4 = (const float4*)rv_p;
    float4*       o4 = (float4*)out_p;

    // ---- stage ref + ref_value halo tile into LDS (coalesced, independent) ----
#pragma unroll
    for (int t = 0; t < 7; ++t) {
        const int idx = tid + t * 256;
        if (idx < L4TOTAL) {
            const int row = idx / L4PERROW;           // 0..5
            const int rem = idx - row * L4PERROW;     // float4 within row
            const int hh  = min(max(h0 + row - 2, 0), 255);   // clamped src row
            const int g   = (bbase + hh * 256 + src_c0) * 8 + rem;
            s_r[idx] = r4[g];
            s_v[idx] = v4[g];
        }
    }

    // main vectors for the 2 owned pixels (independent of staging)
    const int w0 = wt + wv * 8 + pw;
    const float4 m0 = m4[(bbase + (h0 + 0) * 256 + w0) * 8 + cg];
    const float4 m1 = m4[(bbase + (h0 + 1) * 256 + w0) * 8 + cg];

    __syncthreads();

    float  sum0 = 0.f, sum1 = 0.f;
    float4 a0 = make_float4(0.f, 0.f, 0.f, 0.f);
    float4 a1 = make_float4(0.f, 0.f, 0.f, 0.f);

#pragma unroll
    for (int ri = 0; ri < 6; ++ri) {          // neighbor row = h0 + ri - 2
        const int   hh  = h0 + ri - 2;
        const float rok = ((unsigned)hh < 256u) ? 1.0f : 0.0f;
#pragma unroll
        for (int dj = 0; dj < 5; ++dj) {
            const int   ww  = w0 + dj - 2;
            const float msk = rok * (((unsigned)ww < 256u) ? 1.0f : 0.0f);
            const int   lc  = min(max(ww, 0), 255) - src_c0;   // LDS col 0..35
            const int   li  = (ri * LCOLS + lc) * 8 + cg;

            const float4 r = s_r[li];   // contiguous 1KB per wave: conflict-free
            const float4 v = s_v[li];

            if (ri < 5) {   // contributes to output row h0 (row offset ri-2)
                float s = m0.x * r.x + m0.y * r.y + m0.z * r.z + m0.w * r.w;
                s += __shfl_xor(s, 1, 64);
                s += __shfl_xor(s, 2, 64);
                s += __shfl_xor(s, 4, 64);
                const float e  = __expf(s * msk);   // OOB -> exp(0)=1 (zero-pad)
                const float wk = e * msk;
                sum0 += e;
                a0.x += wk * v.x; a0.y += wk * v.y;
                a0.z += wk * v.z; a0.w += wk * v.w;
            }
            if (ri >= 1) {  // contributes to output row h0+1 (row offset ri-3)
                float s = m1.x * r.x + m1.y * r.y + m1.z * r.z + m1.w * r.w;
                s += __shfl_xor(s, 1, 64);
                s += __shfl_xor(s, 2, 64);
                s += __shfl_xor(s, 4, 64);
                const float e  = __expf(s * msk);
                const float wk = e * msk;
                sum1 += e;
                a1.x += wk * v.x; a1.y += wk * v.y;
                a1.z += wk * v.z; a1.w += wk * v.w;
            }
        }
    }

    const float i0 = 1.0f / sum0;
    const float i1 = 1.0f / sum1;
    a0.x *= i0; a0.y *= i0; a0.z *= i0; a0.w *= i0;
    a1.x *= i1; a1.y *= i1; a1.z *= i1; a1.w *= i1;

    o4[(bbase + (h0 + 0) * 256 + w0) * 8 + cg] = a0;
    o4[(bbase + (h0 + 1) * 256 + w0) * 8 + cg] = a1;
}

extern "C" void kernel_launch(void* const* d_in, const int* in_sizes, int n_in,
                              void* d_out, int out_size, void* d_ws, size_t ws_size,
                              hipStream_t stream)
{
    const float* main_p = (const float*)d_in[0];
    const float* ref_p  = (const float*)d_in[1];
    const float* rv_p   = (const float*)d_in[2];
    float*       out_p  = (float*)d_out;

    const int npix   = in_sizes[0] / 32;   // B*H*W = 131072
    const int blocks = npix / 64;          // 64 pixels (32x2 tile) per block
    local_attn_kernel<<<blocks, 256, 0, stream>>>(main_p, ref_p, rv_p, out_p);
}